// Round 1
// baseline (1684.680 us; speedup 1.0000x reference)
//
#include <hip/hip_runtime.h>
#include <math.h>

// Problem constants
constexpr int B = 32, T = 2048, P = 128, K = 256, R = 8, M = 64;
constexpr int BT = B * T;                 // 65536 rows
constexpr int TAU = 5;
constexpr int NSEG = (T + TAU - 1) / TAU; // 410 segments
constexpr float INV_TAU_X = 1.0f / 100.0f;
constexpr float INV_TAU_Z = 1.0f / 100.0f;

// ---------------------------------------------------------------------------
// Generic tiled GEMM: C[n, KOUT] = tanh(A[n, KIN] @ W[KOUT, KIN]^T + bias)
// Block tile = ROWS(=64) rows x KOUT cols (full width -> in-place safe when
// C == A and KIN == KOUT: each block reads only its own rows, writes after
// all reads complete). 256 threads; thread computes RT x CT accumulators.
// ---------------------------------------------------------------------------
template <int KIN, int KOUT, int ROWS, int RT, int CT>
__global__ __launch_bounds__(256) void gemm_tanh_kernel(
    const float* __restrict__ A, const float* __restrict__ W,
    const float* __restrict__ bias, float* __restrict__ C) {
  constexpr int TK = 32;
  constexpr int XG = KOUT / CT;  // thread-groups along cols
  constexpr int YG = ROWS / RT;  // thread-groups along rows
  static_assert(XG * YG == 256, "thread layout");
  static_assert(KIN % TK == 0, "K tiling");

  __shared__ float As[ROWS][TK + 1];
  __shared__ float Ws[KOUT][TK + 1];

  const int tid = threadIdx.x;
  const int tx = tid % XG;
  const int ty = tid / XG;
  const int row0 = blockIdx.x * ROWS;

  float acc[RT][CT];
#pragma unroll
  for (int i = 0; i < RT; ++i)
#pragma unroll
    for (int j = 0; j < CT; ++j) acc[i][j] = 0.f;

  for (int k0 = 0; k0 < KIN; k0 += TK) {
    // Stage A tile (ROWS x TK) — float4 global loads, scalar LDS writes.
    for (int i = tid; i < ROWS * (TK / 4); i += 256) {
      const int r = i / (TK / 4);
      const int c4 = (i % (TK / 4)) * 4;
      const float4 v =
          *(const float4*)&A[(size_t)(row0 + r) * KIN + k0 + c4];
      As[r][c4 + 0] = v.x; As[r][c4 + 1] = v.y;
      As[r][c4 + 2] = v.z; As[r][c4 + 3] = v.w;
    }
    // Stage W tile (KOUT x TK).
    for (int i = tid; i < KOUT * (TK / 4); i += 256) {
      const int r = i / (TK / 4);
      const int c4 = (i % (TK / 4)) * 4;
      const float4 v = *(const float4*)&W[(size_t)r * KIN + k0 + c4];
      Ws[r][c4 + 0] = v.x; Ws[r][c4 + 1] = v.y;
      Ws[r][c4 + 2] = v.z; Ws[r][c4 + 3] = v.w;
    }
    __syncthreads();

#pragma unroll
    for (int kk = 0; kk < TK; ++kk) {
      float a[RT], b[CT];
#pragma unroll
      for (int i = 0; i < RT; ++i) a[i] = As[ty * RT + i][kk];
#pragma unroll
      for (int j = 0; j < CT; ++j) b[j] = Ws[tx + XG * j][kk];
#pragma unroll
      for (int i = 0; i < RT; ++i)
#pragma unroll
        for (int j = 0; j < CT; ++j) acc[i][j] += a[i] * b[j];
    }
    __syncthreads();
  }

  // Epilogue: bias + tanh, write to global.
#pragma unroll
  for (int i = 0; i < RT; ++i) {
    const size_t r = (size_t)row0 + ty * RT + i;
#pragma unroll
    for (int j = 0; j < CT; ++j) {
      const int c = tx + XG * j;
      C[r * KOUT + c] = tanhf(acc[i][j] + bias[c]);
    }
  }
}

// ---------------------------------------------------------------------------
// Scan kernel. The reset every TAU=5 steps makes segments independent:
// chain = (batch b, segment seg starting at t0 = seg*5) seeded with
// x_seq[b, t0, :], z_seq[b, t0, :]. One wave (64 lanes) per chain:
//   lane m holds z[m]; lane l holds x[l + 64j], j=0..3.
// Writes x states to ws (decoded later as a batched GEMM) and z_pred to out.
// ---------------------------------------------------------------------------
__global__ __launch_bounds__(256) void scan_kernel(
    const float* __restrict__ x_seq,  // (B,T,K)
    const float* __restrict__ z_seq,  // (B,T,M)
    const float* __restrict__ Lm,     // (K,R)
    const float* __restrict__ Rm,     // (K,R)
    const float* __restrict__ Wz,     // (M,M)
    const float* __restrict__ Az_w,   // (R,M)
    const float* __restrict__ Az_b,   // (R)
    float* __restrict__ x_states,     // (B,T,K)
    float* __restrict__ z_pred) {     // (B,T,M)
  __shared__ float Wz_s[M][M + 1];  // stride 65 -> conflict-free matvec reads
  __shared__ float Az_s[R][M];
  __shared__ float Azb_s[R];
  __shared__ float Lt_s[R][K];  // transposed: Lt[r][k]
  __shared__ float Rt_s[R][K];
  __shared__ float tz_s[4][M];  // per-wave tanh(z) broadcast buffer

  const int tid = threadIdx.x;
  for (int i = tid; i < M * M; i += 256) Wz_s[i >> 6][i & 63] = Wz[i];
  for (int i = tid; i < R * M; i += 256) Az_s[i >> 6][i & 63] = Az_w[i];
  if (tid < R) Azb_s[tid] = Az_b[tid];
  for (int i = tid; i < K * R; i += 256) {
    const int k = i / R, r = i % R;
    Lt_s[r][k] = Lm[i];
    Rt_s[r][k] = Rm[i];
  }
  __syncthreads();

  const int wave = tid >> 6;
  const int lane = tid & 63;
  const int chain = blockIdx.x * 4 + wave;  // grid sized so chain < B*NSEG
  const int b = chain / NSEG;
  const int seg = chain % NSEG;
  const int t0 = seg * TAU;

  // Seed state from the (post-reset) carry.
  float x[4], z;
  {
    const float* xs0 = &x_seq[((size_t)b * T + t0) * K];
#pragma unroll
    for (int j = 0; j < 4; ++j) x[j] = xs0[lane + 64 * j];
    z = z_seq[((size_t)b * T + t0) * M + lane];
  }

  for (int tt = 0; tt < TAU; ++tt) {
    const int t = t0 + tt;
    // --- z update: z += (tanh(z) @ Wz^T - z) / TAU_Z
    const float tz = tanhf(z);
    tz_s[wave][lane] = tz;
    __syncthreads();
    float zacc = 0.f;
#pragma unroll 8
    for (int j = 0; j < M; ++j) zacc += tz_s[wave][j] * Wz_s[lane][j];
    const float znew = z + (zacc - z) * INV_TAU_Z;
    __syncthreads();  // all waves done reading tz_s before next overwrite

    // --- s = sigmoid(z_new @ Az_w^T + Az_b), broadcast to all lanes
    float s[R];
#pragma unroll
    for (int r = 0; r < R; ++r) {
      float p = znew * Az_s[r][lane];
#pragma unroll
      for (int off = 32; off > 0; off >>= 1) p += __shfl_xor(p, off, 64);
      s[r] = 1.f / (1.f + expf(-(p + Azb_s[r])));
    }

    // --- x update: u = tanh(x) @ L ; v = u * s ; x += (v @ Rm^T - x)/TAU_X
    float tx4[4];
#pragma unroll
    for (int j = 0; j < 4; ++j) tx4[j] = tanhf(x[j]);
    float v[R];
#pragma unroll
    for (int r = 0; r < R; ++r) {
      float p = 0.f;
#pragma unroll
      for (int j = 0; j < 4; ++j) p += tx4[j] * Lt_s[r][lane + 64 * j];
#pragma unroll
      for (int off = 32; off > 0; off >>= 1) p += __shfl_xor(p, off, 64);
      v[r] = p * s[r];
    }
#pragma unroll
    for (int j = 0; j < 4; ++j) {
      float xacc = 0.f;
#pragma unroll
      for (int r = 0; r < R; ++r) xacc += v[r] * Rt_s[r][lane + 64 * j];
      x[j] = x[j] + (xacc - x[j]) * INV_TAU_X;
    }

    // --- store (segment 409 computes t=2048,2049 but never stores them)
    if (t < T) {
      float* xd = &x_states[((size_t)b * T + t) * K];
#pragma unroll
      for (int j = 0; j < 4; ++j) xd[lane + 64 * j] = x[j];
      z_pred[((size_t)b * T + t) * M + lane] = znew;
    }
    z = znew;
  }
}

// ---------------------------------------------------------------------------
// Launch. Buffer plan (all device-side, stream-ordered):
//   ws[0 .. 64MB)    : x_seq   (BT x K fp32)
//   ws[64 .. 128MB)  : x_states(BT x K fp32)
//   d_out regions: 0 x_pred (BT*P), 1 x_recon (BT*P), 2 z_pred (BT*M),
//                  3 z_seq (BT*M). Regions 0+1 double as the 64MB encoder
//   scratch (BT x K), region 2 as the z-encoder scratch — both fully
//   overwritten with final values afterwards.
// ---------------------------------------------------------------------------
extern "C" void kernel_launch(void* const* d_in, const int* in_sizes, int n_in,
                              void* d_out, int out_size, void* d_ws,
                              size_t ws_size, hipStream_t stream) {
  const float* in_seq = (const float*)d_in[0];
  const float* Lm    = (const float*)d_in[1];
  const float* Rm    = (const float*)d_in[2];
  const float* Wz    = (const float*)d_in[3];
  const float* Az_w  = (const float*)d_in[4];
  const float* Az_b  = (const float*)d_in[5];
  const float* ex1_w = (const float*)d_in[6];
  const float* ex1_b = (const float*)d_in[7];
  const float* ex2_w = (const float*)d_in[8];
  const float* ex2_b = (const float*)d_in[9];
  const float* ex3_w = (const float*)d_in[10];
  const float* ex3_b = (const float*)d_in[11];
  const float* ez1_w = (const float*)d_in[12];
  const float* ez1_b = (const float*)d_in[13];
  const float* ez2_w = (const float*)d_in[14];
  const float* ez2_b = (const float*)d_in[15];
  const float* ez3_w = (const float*)d_in[16];
  const float* ez3_b = (const float*)d_in[17];
  const float* de1_w = (const float*)d_in[18];
  const float* de1_b = (const float*)d_in[19];
  const float* de2_w = (const float*)d_in[20];
  const float* de2_b = (const float*)d_in[21];

  float* out = (float*)d_out;
  float* x_pred  = out;                        // BT*P
  float* x_recon = out + (size_t)BT * P;       // BT*P
  float* z_pred  = out + (size_t)2 * BT * P;   // BT*M
  float* z_seq   = out + (size_t)2 * BT * P + (size_t)BT * M;  // BT*M
  float* S0   = out;     // 64MB scratch (regions 0+1) for x-encoder
  float* zscr = z_pred;  // 16MB scratch (region 2) for z-encoder

  float* ws = (float*)d_ws;
  float* x_seq    = ws;                    // BT*K
  float* x_states = ws + (size_t)BT * K;   // BT*K

  const dim3 blk(256);
  const dim3 grd(BT / 64);  // 1024 row-blocks

  // z encoder: 128 -> 64 -> 64 -> 64 (layer 2 in place; full-width tiles)
  gemm_tanh_kernel<128, 64, 64, 4, 4><<<grd, blk, 0, stream>>>(in_seq, ez1_w, ez1_b, zscr);
  gemm_tanh_kernel< 64, 64, 64, 4, 4><<<grd, blk, 0, stream>>>(zscr, ez2_w, ez2_b, zscr);
  gemm_tanh_kernel< 64, 64, 64, 4, 4><<<grd, blk, 0, stream>>>(zscr, ez3_w, ez3_b, z_seq);

  // x encoder: 128 -> 256 -> 256 -> 256 (layer 2 in place on S0)
  gemm_tanh_kernel<128, 256, 64, 8, 8><<<grd, blk, 0, stream>>>(in_seq, ex1_w, ex1_b, S0);
  gemm_tanh_kernel<256, 256, 64, 8, 8><<<grd, blk, 0, stream>>>(S0, ex2_w, ex2_b, S0);
  gemm_tanh_kernel<256, 256, 64, 8, 8><<<grd, blk, 0, stream>>>(S0, ex3_w, ex3_b, x_seq);

  // scan: 32*410 = 13120 chains, 4 waves/block -> 3280 blocks
  scan_kernel<<<dim3((B * NSEG) / 4), blk, 0, stream>>>(
      x_seq, z_seq, Lm, Rm, Wz, Az_w, Az_b, x_states, z_pred);

  // decoder on scan states: 256 -> 256 (in place) -> 128 -> x_pred
  gemm_tanh_kernel<256, 256, 64, 8, 8><<<grd, blk, 0, stream>>>(x_states, de1_w, de1_b, x_states);
  gemm_tanh_kernel<256, 128, 64, 4, 8><<<grd, blk, 0, stream>>>(x_states, de2_w, de2_b, x_pred);

  // decoder on x_seq: 256 -> 256 (in place) -> 128 -> x_recon
  gemm_tanh_kernel<256, 256, 64, 8, 8><<<grd, blk, 0, stream>>>(x_seq, de1_w, de1_b, x_seq);
  gemm_tanh_kernel<256, 128, 64, 4, 8><<<grd, blk, 0, stream>>>(x_seq, de2_w, de2_b, x_recon);
}

// Round 3
// 715.309 us; speedup vs baseline: 2.3552x; 2.3552x over previous
//
#include <hip/hip_runtime.h>
#include <math.h>

// Problem constants
constexpr int B = 32, T = 2048, P = 128, K = 256, R = 8, M = 64;
constexpr int BT = B * T;                 // 65536 rows
constexpr int TAU = 5;
constexpr int NSEG = (T + TAU - 1) / TAU; // 410 segments
constexpr float INV_TAU_X = 1.0f / 100.0f;
constexpr float INV_TAU_Z = 1.0f / 100.0f;

typedef short bf16x8 __attribute__((ext_vector_type(8)));
typedef float f32x4 __attribute__((ext_vector_type(4)));

// fp32 -> bf16 round-to-nearest-even.
static __device__ __forceinline__ short f2bf(float f) {
  unsigned u = __builtin_bit_cast(unsigned, f);
  u += 0x7FFF + ((u >> 16) & 1);
  return (short)(u >> 16);
}
static __device__ __forceinline__ float bf2f(short h) {
  unsigned u = ((unsigned)(unsigned short)h) << 16;
  return __builtin_bit_cast(float, u);
}

// ---------------------------------------------------------------------------
// C[n, KOUT] = tanh(A[n, KIN] @ W[KOUT, KIN]^T + bias)  via SPLIT-bf16 MFMA:
// each fp32 operand x = x_hi + x_lo (two bf16), product computed as
// hi*hi + lo*hi + hi*lo (3 MFMAs, fp32 acc) -> ~2^-16 relative error,
// fp32-quality output. These layers are HBM-bound, so 3x MFMA is ~free.
// Block tile 128 x BN, BK = 64, 4 waves (warpM = wave&1 over 64 rows,
// warpN = wave>>1 over BN/2 cols). LDS row stride 72 bf16 = 144 B (16-B
// aligned, conflict-free). Frag layouts per m89/m91-verified mappings.
// ---------------------------------------------------------------------------
template <int KIN, int KOUT, int BN>
__global__ __launch_bounds__(256) void gemm_tanh_mfma(
    const float* __restrict__ A, const float* __restrict__ W,
    const float* __restrict__ bias, float* __restrict__ C) {
  constexpr int BK = 64;
  constexpr int LDA = BK + 8;   // 72 bf16
  constexpr int WNT = BN / 32;  // col sub-tiles per wave (2 or 4)
  static_assert(KIN % BK == 0, "K tiling");

  __shared__ short AsH[128 * LDA];
  __shared__ short AsL[128 * LDA];
  __shared__ short BsH[BN * LDA];
  __shared__ short BsL[BN * LDA];

  const int tid = threadIdx.x;
  const int wave = tid >> 6, lane = tid & 63;
  const int l16 = lane & 15, quad = lane >> 4;
  const int warpM = wave & 1, warpN = wave >> 1;
  const int row0 = blockIdx.x * 128;
  const int col0 = blockIdx.y * BN;

  f32x4 acc[4][WNT];
#pragma unroll
  for (int i = 0; i < 4; ++i)
#pragma unroll
    for (int j = 0; j < WNT; ++j) acc[i][j] = (f32x4){0.f, 0.f, 0.f, 0.f};

  for (int k0 = 0; k0 < KIN; k0 += BK) {
    // Stage A: 128 rows x 64 k, split hi/lo.
#pragma unroll
    for (int c = tid; c < 128 * 8; c += 256) {
      const int r = c >> 3, kc = (c & 7) * 8;
      const float* src = &A[(size_t)(row0 + r) * KIN + k0 + kc];
      const float4 v0 = *(const float4*)src;
      const float4 v1 = *(const float4*)(src + 4);
      float f[8] = {v0.x, v0.y, v0.z, v0.w, v1.x, v1.y, v1.z, v1.w};
      bf16x8 ph, pl;
#pragma unroll
      for (int q = 0; q < 8; ++q) {
        const short h = f2bf(f[q]);
        ph[q] = h;
        pl[q] = f2bf(f[q] - bf2f(h));
      }
      *(bf16x8*)&AsH[r * LDA + kc] = ph;
      *(bf16x8*)&AsL[r * LDA + kc] = pl;
    }
    // Stage B (weight rows col0 .. col0+BN), split hi/lo.
#pragma unroll
    for (int c = tid; c < BN * 8; c += 256) {
      const int r = c >> 3, kc = (c & 7) * 8;
      const float* src = &W[(size_t)(col0 + r) * KIN + k0 + kc];
      const float4 v0 = *(const float4*)src;
      const float4 v1 = *(const float4*)(src + 4);
      float f[8] = {v0.x, v0.y, v0.z, v0.w, v1.x, v1.y, v1.z, v1.w};
      bf16x8 ph, pl;
#pragma unroll
      for (int q = 0; q < 8; ++q) {
        const short h = f2bf(f[q]);
        ph[q] = h;
        pl[q] = f2bf(f[q] - bf2f(h));
      }
      *(bf16x8*)&BsH[r * LDA + kc] = ph;
      *(bf16x8*)&BsL[r * LDA + kc] = pl;
    }
    __syncthreads();

#pragma unroll
    for (int kk = 0; kk < BK; kk += 32) {
      const int ko = kk + quad * 8;
      bf16x8 ah[4], al[4], bh[WNT], bl[WNT];
#pragma unroll
      for (int i = 0; i < 4; ++i) {
        const int off = (warpM * 64 + i * 16 + l16) * LDA + ko;
        ah[i] = *(const bf16x8*)&AsH[off];
        al[i] = *(const bf16x8*)&AsL[off];
      }
#pragma unroll
      for (int j = 0; j < WNT; ++j) {
        const int off = (warpN * WNT * 16 + j * 16 + l16) * LDA + ko;
        bh[j] = *(const bf16x8*)&BsH[off];
        bl[j] = *(const bf16x8*)&BsL[off];
      }
#pragma unroll
      for (int i = 0; i < 4; ++i)
#pragma unroll
        for (int j = 0; j < WNT; ++j) {
          acc[i][j] = __builtin_amdgcn_mfma_f32_16x16x32_bf16(ah[i], bh[j],
                                                              acc[i][j], 0, 0, 0);
          acc[i][j] = __builtin_amdgcn_mfma_f32_16x16x32_bf16(al[i], bh[j],
                                                              acc[i][j], 0, 0, 0);
          acc[i][j] = __builtin_amdgcn_mfma_f32_16x16x32_bf16(ah[i], bl[j],
                                                              acc[i][j], 0, 0, 0);
        }
    }
    __syncthreads();
  }

  // Epilogue: bias + tanh, fp32 stores. C/D map: col=lane&15, row=quad*4+reg.
#pragma unroll
  for (int j = 0; j < WNT; ++j) {
    const int col = col0 + warpN * WNT * 16 + j * 16 + l16;
    const float bj = bias[col];
#pragma unroll
    for (int i = 0; i < 4; ++i) {
      const int rbase = row0 + warpM * 64 + i * 16 + quad * 4;
#pragma unroll
      for (int r = 0; r < 4; ++r)
        C[(size_t)(rbase + r) * KOUT + col] = tanhf(acc[i][j][r] + bj);
    }
  }
}

// ---------------------------------------------------------------------------
// Scan kernel: reset every TAU=5 steps makes segments independent; one wave
// per (batch, segment) chain. All fp32.
// ---------------------------------------------------------------------------
__global__ __launch_bounds__(256) void scan_kernel(
    const float* __restrict__ x_seq,  // (B,T,K)
    const float* __restrict__ z_seq,  // (B,T,M)
    const float* __restrict__ Lm,     // (K,R)
    const float* __restrict__ Rm,     // (K,R)
    const float* __restrict__ Wz,     // (M,M)
    const float* __restrict__ Az_w,   // (R,M)
    const float* __restrict__ Az_b,   // (R)
    float* __restrict__ x_states,     // (B,T,K)
    float* __restrict__ z_pred) {     // (B,T,M)
  __shared__ float Wz_s[M][M + 1];
  __shared__ float Az_s[R][M];
  __shared__ float Azb_s[R];
  __shared__ float Lt_s[R][K];
  __shared__ float Rt_s[R][K];
  __shared__ float tz_s[4][M];

  const int tid = threadIdx.x;
  for (int i = tid; i < M * M; i += 256) Wz_s[i >> 6][i & 63] = Wz[i];
  for (int i = tid; i < R * M; i += 256) Az_s[i >> 6][i & 63] = Az_w[i];
  if (tid < R) Azb_s[tid] = Az_b[tid];
  for (int i = tid; i < K * R; i += 256) {
    const int k = i / R, r = i % R;
    Lt_s[r][k] = Lm[i];
    Rt_s[r][k] = Rm[i];
  }
  __syncthreads();

  const int wave = tid >> 6;
  const int lane = tid & 63;
  const int chain = blockIdx.x * 4 + wave;
  const int b = chain / NSEG;
  const int seg = chain % NSEG;
  const int t0 = seg * TAU;

  float x[4], z;
  {
    const float* xs0 = &x_seq[((size_t)b * T + t0) * K];
#pragma unroll
    for (int j = 0; j < 4; ++j) x[j] = xs0[lane + 64 * j];
    z = z_seq[((size_t)b * T + t0) * M + lane];
  }

  for (int tt = 0; tt < TAU; ++tt) {
    const int t = t0 + tt;
    const float tz = tanhf(z);
    tz_s[wave][lane] = tz;
    __syncthreads();
    float zacc = 0.f;
#pragma unroll 8
    for (int j = 0; j < M; ++j) zacc += tz_s[wave][j] * Wz_s[lane][j];
    const float znew = z + (zacc - z) * INV_TAU_Z;
    __syncthreads();

    float s[R];
#pragma unroll
    for (int r = 0; r < R; ++r) {
      float p = znew * Az_s[r][lane];
#pragma unroll
      for (int off = 32; off > 0; off >>= 1) p += __shfl_xor(p, off, 64);
      s[r] = 1.f / (1.f + expf(-(p + Azb_s[r])));
    }

    float tx4[4];
#pragma unroll
    for (int j = 0; j < 4; ++j) tx4[j] = tanhf(x[j]);
    float v[R];
#pragma unroll
    for (int r = 0; r < R; ++r) {
      float p = 0.f;
#pragma unroll
      for (int j = 0; j < 4; ++j) p += tx4[j] * Lt_s[r][lane + 64 * j];
#pragma unroll
      for (int off = 32; off > 0; off >>= 1) p += __shfl_xor(p, off, 64);
      v[r] = p * s[r];
    }
#pragma unroll
    for (int j = 0; j < 4; ++j) {
      float xacc = 0.f;
#pragma unroll
      for (int r = 0; r < R; ++r) xacc += v[r] * Rt_s[r][lane + 64 * j];
      x[j] = x[j] + (xacc - x[j]) * INV_TAU_X;
    }

    if (t < T) {
      float* xd = &x_states[((size_t)b * T + t) * K];
#pragma unroll
      for (int j = 0; j < 4; ++j) xd[lane + 64 * j] = x[j];
      z_pred[((size_t)b * T + t) * M + lane] = znew;
    }
    z = znew;
  }
}

// ---------------------------------------------------------------------------
// Schedule (ping-pong between ws0/ws1; x_recon decoded before the scan so
// ws1 is free for x_states):
//   1. ex1: in_seq->ws0; ex2: ws0->ws1; ex3: ws1->ws0 (= x_seq)
//   2. de1: ws0->ws1; de2: ws1->x_recon
//   3. z enc: in_seq->r3; r3->r2; r2->r3 (= z_seq final)
//   4. scan: ws0 + r3 -> x_states(ws1), z_pred(r2)
//   5. de1: ws1->ws0; de2: ws0->x_pred
// ---------------------------------------------------------------------------
extern "C" void kernel_launch(void* const* d_in, const int* in_sizes, int n_in,
                              void* d_out, int out_size, void* d_ws,
                              size_t ws_size, hipStream_t stream) {
  const float* in_seq = (const float*)d_in[0];
  const float* Lm    = (const float*)d_in[1];
  const float* Rm    = (const float*)d_in[2];
  const float* Wz    = (const float*)d_in[3];
  const float* Az_w  = (const float*)d_in[4];
  const float* Az_b  = (const float*)d_in[5];
  const float* ex1_w = (const float*)d_in[6];
  const float* ex1_b = (const float*)d_in[7];
  const float* ex2_w = (const float*)d_in[8];
  const float* ex2_b = (const float*)d_in[9];
  const float* ex3_w = (const float*)d_in[10];
  const float* ex3_b = (const float*)d_in[11];
  const float* ez1_w = (const float*)d_in[12];
  const float* ez1_b = (const float*)d_in[13];
  const float* ez2_w = (const float*)d_in[14];
  const float* ez2_b = (const float*)d_in[15];
  const float* ez3_w = (const float*)d_in[16];
  const float* ez3_b = (const float*)d_in[17];
  const float* de1_w = (const float*)d_in[18];
  const float* de1_b = (const float*)d_in[19];
  const float* de2_w = (const float*)d_in[20];
  const float* de2_b = (const float*)d_in[21];

  float* out = (float*)d_out;
  float* x_pred  = out;                                        // BT*P
  float* x_recon = out + (size_t)BT * P;                       // BT*P
  float* z_pred  = out + (size_t)2 * BT * P;                   // BT*M (r2)
  float* z_seq   = out + (size_t)2 * BT * P + (size_t)BT * M;  // BT*M (r3)

  float* ws = (float*)d_ws;
  float* ws0 = ws;                  // BT*K
  float* ws1 = ws + (size_t)BT * K; // BT*K

  const dim3 blk(256);
  const dim3 g2(BT / 128, 2);  // KOUT=256
  const dim3 g1(BT / 128, 1);  // KOUT=128 or 64

  // x encoder: 128 -> 256 -> 256 -> 256
  gemm_tanh_mfma<128, 256, 128><<<g2, blk, 0, stream>>>(in_seq, ex1_w, ex1_b, ws0);
  gemm_tanh_mfma<256, 256, 128><<<g2, blk, 0, stream>>>(ws0, ex2_w, ex2_b, ws1);
  gemm_tanh_mfma<256, 256, 128><<<g2, blk, 0, stream>>>(ws1, ex3_w, ex3_b, ws0);

  // x_recon decoder (before scan so ws1 can be reused for x_states)
  gemm_tanh_mfma<256, 256, 128><<<g2, blk, 0, stream>>>(ws0, de1_w, de1_b, ws1);
  gemm_tanh_mfma<256, 128, 128><<<g1, blk, 0, stream>>>(ws1, de2_w, de2_b, x_recon);

  // z encoder: 128 -> 64 -> 64 -> 64   (r3 -> r2 -> r3)
  gemm_tanh_mfma<128, 64, 64><<<g1, blk, 0, stream>>>(in_seq, ez1_w, ez1_b, z_seq);
  gemm_tanh_mfma< 64, 64, 64><<<g1, blk, 0, stream>>>(z_seq, ez2_w, ez2_b, z_pred);
  gemm_tanh_mfma< 64, 64, 64><<<g1, blk, 0, stream>>>(z_pred, ez3_w, ez3_b, z_seq);

  // scan: x_states -> ws1, z_pred -> r2
  scan_kernel<<<dim3((B * NSEG) / 4), blk, 0, stream>>>(
      ws0, z_seq, Lm, Rm, Wz, Az_w, Az_b, ws1, z_pred);

  // x_pred decoder
  gemm_tanh_mfma<256, 256, 128><<<g2, blk, 0, stream>>>(ws1, de1_w, de1_b, ws0);
  gemm_tanh_mfma<256, 128, 128><<<g1, blk, 0, stream>>>(ws0, de2_w, de2_b, x_pred);
}